// Round 1
// baseline (278.018 us; speedup 1.0000x reference)
//
#include <hip/hip_runtime.h>
#include <hip/hip_bf16.h>
#include <stdint.h>

// ---------------------------------------------------------------------------
// TensorizedGRU: m[b,l] = sum_{j,k} s[b,j] x[b,k] W[l,j,k]  (l in [0,256): W1||W2)
// R10 = R9 + LDS-return-path fix (the diagnosed bottleneck):
//  - Theory: R9's 8x ds_read_b128 s-broadcasts per wave-iter = 8KB replicated
//    return traffic; CU LDS return = 128B/cyc -> 512-640cyc/round vs 310cyc
//    MFMA demand at 8 waves/CU => MfmaUtil cap ~48% (measured 44.6%).
//  - Fix (a): s staged in LDS as f16 (rel err 2^-11, << bf16 noise in x/W);
//    sv reads become ds_read_b64 (half the return bytes); scale-accumulate
//    uses (float)h * m0 -> v_fma_mix_f32 / cvt+pk_fma, still f32 math.
//  - Fix (b): 64-row m-tiles, grid 1024 (ks8 x nt2 x mt64) -> 4 blocks/CU
//    (16 waves/CU). Keeps nf=2 per wave so sv-bytes-per-MFMA is unchanged.
//    racc 64->32 VGPR, a 64->32 VGPR => fits __launch_bounds__(256,4).
//  - prep / epilogue / ws layout identical to R9. Mpart stays 8 slices.
// ws layout:
//   Wt   bf16 [256][65536]  @ 0          (33,554,432 B)  fragment-ordered
//   x_bf bf16 [4096][256]   @ 32MiB+2MiB ( 2,097,152 B)
//   Mpart f32 [8][4096][256]@ +2MiB      (33,554,432 B)
// ---------------------------------------------------------------------------

typedef short bf8 __attribute__((ext_vector_type(8)));   // 8 bf16 = 4 VGPRs
typedef float f32x4 __attribute__((ext_vector_type(4)));
typedef _Float16 h4 __attribute__((ext_vector_type(4))); // 4 f16 = 2 VGPRs

static constexpr size_t WT_OFF  = 0;
static constexpr size_t XBF_OFF = 33554432 + 2097152;
static constexpr size_t MP_OFF  = XBF_OFF + 2097152;

// round-to-nearest-even f32 -> bf16 (finite inputs only)
__device__ __forceinline__ unsigned f2bf(float f) {
    unsigned u = __builtin_bit_cast(unsigned, f);
    return (u + 0x7fffu + ((u >> 16) & 1u)) >> 16;
}
__device__ __forceinline__ unsigned pack2bf(float a, float b) {
    return f2bf(a) | (f2bf(b) << 16);
}

// ---------------- prep: fragment-ordered Wt (wave-per-frag) + x cast --------
// Fragment f = ((n16*1024 + kchunk)*2 + kst), f in [0, 32768).
// Blocks 0..8191: 4 waves/block, wave w makes frag f = bx*4 + w.
// Blocks 8192..9215: x = in0||in1 -> bf16.
__global__ void prep_wx(const float* __restrict__ W1, const float* __restrict__ W2,
                        const float* __restrict__ in0, const float* __restrict__ in1,
                        uint4* __restrict__ Wt, unsigned* __restrict__ x_bf) {
    int bx = blockIdx.x;
    if (bx < 8192) {
        const int tid  = threadIdx.x;
        const int lane = tid & 63, wave = tid >> 6;
        const unsigned f = bx * 4 + wave;
        const unsigned n16 = f >> 11;
        const unsigned kchunk = (f >> 1) & 1023u;
        const unsigned kst = f & 1u;
        const unsigned n = n16 * 16 + (lane & 15);
        const unsigned K = kchunk * 64 + kst * 32 + (lane >> 4) * 8;
        const float* src = (n < 128 ? W1 + ((size_t)n << 16)
                                    : W2 + ((size_t)(n - 128) << 16)) + K;
        float4 a = ((const float4*)src)[0];
        float4 b = ((const float4*)src)[1];
        uint4 o;
        o.x = pack2bf(a.x, a.y); o.y = pack2bf(a.z, a.w);
        o.z = pack2bf(b.x, b.y); o.w = pack2bf(b.z, b.w);
        Wt[(size_t)f * 64 + lane] = o;        // contiguous 1KB per wave
    } else {
        unsigned v = (bx - 8192) * 256 + threadIdx.x; // 262,144 units of 4 elems
        unsigned b = v >> 6;
        unsigned j4 = (v & 63u) * 4u;
        const float* src = (j4 < 128) ? (in0 + (size_t)b * 128 + j4)
                                      : (in1 + (size_t)b * 128 + (j4 - 128));
        float4 a = *(const float4*)src;
        uint2 o;
        o.x = pack2bf(a.x, a.y);
        o.y = pack2bf(a.z, a.w);
        ((uint2*)x_bf)[v] = o;
    }
}

// ---------------- main GEMM: 64x128 tile, split-K=8, barrier-free -----------
// grid 1024: ks = bx&7 (XCD-pinned), nt = (bx>>3)&1, mt = bx>>4 (0..63).
// block 256 = 4 waves; wave w owns n-cols [w*32, w*32+32), all 64 m-rows.
__launch_bounds__(256, 4)
__global__ void gemm_p(const unsigned char* __restrict__ Wt,
                       const float* __restrict__ st0, const float* __restrict__ st1,
                       const __hip_bfloat16* __restrict__ x_bf,
                       float* __restrict__ Mpart) {
    const int bx = blockIdx.x;
    const int ks = bx & 7;                  // split-K slice, pinned per XCD
    const int nt = (bx >> 3) & 1;
    const int mt = bx >> 4;                 // 0..63
    const int b0 = mt << 6, n0 = nt << 7;
    const int tid  = threadIdx.x;
    const int lane = tid & 63, wave = tid >> 6;
    const int l15 = lane & 15, l4 = lane >> 4;

    // s tile as f16: [32 j][64 r]  (4 KiB; half the LDS return bytes of f32)
    __shared__ __align__(16) _Float16 SlH[32 * 64];
    for (int idx = tid; idx < 2048; idx += 256) {
        int j = idx >> 6, r = idx & 63;     // r-fast: b16 writes <=2-way/bank
        int jg = ks * 32 + j;
        float v = (jg < 128) ? st0[(size_t)(b0 + r) * 128 + jg]
                             : st1[(size_t)(b0 + r) * 128 + (jg - 128)];
        SlH[j * 64 + r] = (_Float16)v;
    }
    __syncthreads();                        // the ONLY barrier

    // B-frag bases, fragment-ordered Wt (identical layout to R9):
    // n16(nf) = nt*8 + wave*2 + nf; frag addr = ((n16*1024+kchunk)*2+kst)*1024 + lane*16
    const unsigned char* rbn[2];
    #pragma unroll
    for (int nf = 0; nf < 2; ++nf)
        rbn[nf] = Wt + ((size_t)(nt * 8 + wave * 2 + nf) << 21) + lane * 16;
    const _Float16* sB = SlH + l4 * 4;

    f32x4 racc[4][2];
    #pragma unroll
    for (int mf = 0; mf < 4; ++mf)
        #pragma unroll
        for (int nf = 0; nf < 2; ++nf)
            racc[mf][nf] = (f32x4){0.f, 0.f, 0.f, 0.f};
    const f32x4 zacc = (f32x4){0.f, 0.f, 0.f, 0.f};

    // chunk c in [0,128): q = c>>5 (x-quadrant), j = c&31 (local j)
    // kchunk(c) = ((ks*32 + j)*4 + q); byte offset = kchunk*2048 (+ kst*1024)
    auto kof = [&](int c) { return (size_t)(((ks * 32 + (c & 31)) * 4 + (c >> 5)) * 2048); };

    bf8 buf[2][2][2];                       // [ping][nf][kst]
    #pragma unroll
    for (int nf = 0; nf < 2; ++nf)
        #pragma unroll
        for (int kst = 0; kst < 2; ++kst)
            buf[0][nf][kst] = *(const bf8*)(rbn[nf] + kof(0) + kst * 1024);

    bf8 a[4][2];                            // x A-frags, reloaded at q boundary

    #pragma unroll 2
    for (int c = 0; c < 128; ++c) {
        const int pp = c & 1;
        const int q = c >> 5, j = c & 31;
        if (j == 0) {                       // new x-quadrant: reload A-frags
            const __hip_bfloat16* xb = x_bf + q * 64 + l4 * 8;
            #pragma unroll
            for (int mf = 0; mf < 4; ++mf)
                #pragma unroll
                for (int kst = 0; kst < 2; ++kst)
                    a[mf][kst] = *(const bf8*)(xb + (size_t)(b0 + mf * 16 + l15) * 256 + kst * 32);
        }
        // prefetch next chunk's B-frags (wraps to 0 on last iter: harmless)
        {
            const size_t k1 = kof((c + 1) & 127);
            #pragma unroll
            for (int nf = 0; nf < 2; ++nf)
                #pragma unroll
                for (int kst = 0; kst < 2; ++kst)
                    buf[pp ^ 1][nf][kst] = *(const bf8*)(rbn[nf] + k1 + kst * 1024);
        }
        // 16 MFMA + mixed-precision scale-accumulate (s applied at f32)
        #pragma unroll
        for (int mf = 0; mf < 4; ++mf) {
            h4 hv = *(const h4*)(sB + j * 64 + mf * 16);   // ds_read_b64 broadcast
            f32x4 sf;
            #pragma unroll
            for (int r = 0; r < 4; ++r) sf[r] = (float)hv[r];
            #pragma unroll
            for (int nf = 0; nf < 2; ++nf) {
                f32x4 m0 = __builtin_amdgcn_mfma_f32_16x16x32_bf16(a[mf][0], buf[pp][nf][0], zacc, 0, 0, 0);
                m0 = __builtin_amdgcn_mfma_f32_16x16x32_bf16(a[mf][1], buf[pp][nf][1], m0, 0, 0, 0);
                racc[mf][nf] += sf * m0;
            }
        }
    }

    // split-K partial stores (regular stores: producer->consumer coherence)
    float* mp = Mpart + ((size_t)ks << 20);
    #pragma unroll
    for (int mf = 0; mf < 4; ++mf)
        #pragma unroll
        for (int nf = 0; nf < 2; ++nf) {
            int b = b0 + mf * 16 + l4 * 4;
            int n = n0 + wave * 32 + nf * 16 + l15;
            #pragma unroll
            for (int r = 0; r < 4; ++r)
                mp[(size_t)(b + r) * 256 + n] = racc[mf][nf][r];
        }
}

// ---------------- epilogue: reduce split-K, s@W3, activations, blend --------
__global__ void epilogue(const float* __restrict__ st0, const float* __restrict__ st1,
                         const float* __restrict__ b1, const float* __restrict__ b2,
                         const float* __restrict__ W3, const float* __restrict__ Mpart,
                         float* __restrict__ out) {
    const int tid = threadIdx.x;
    const int h = tid & 127, rg = tid >> 7;          // rg in {0,1}
    const int bbase = blockIdx.x * 8;                // 8 rows per block
    __shared__ float srow[8][256];
    #pragma unroll
    for (int i = 0; i < 8; ++i) {
        int idx = i * 256 + tid;
        int r = idx >> 8, j = idx & 255;
        float v = (j < 128) ? st0[(size_t)(bbase + r) * 128 + j]
                            : st1[(size_t)(bbase + r) * 128 + (j - 128)];
        srow[r][j] = v;
    }
    __syncthreads();
    float acc0 = 0.f, acc1 = 0.f, acc2 = 0.f, acc3 = 0.f;
    for (int j = 0; j < 256; ++j) {
        float w = W3[j * 128 + h];
        acc0 += srow[rg][j] * w;
        acc1 += srow[rg + 2][j] * w;
        acc2 += srow[rg + 4][j] * w;
        acc3 += srow[rg + 6][j] * w;
    }
    float accs[4] = {acc0, acc1, acc2, acc3};
    float bb1 = b1[h], bb2 = b2[h];
    #pragma unroll
    for (int i = 0; i < 4; ++i) {
        int b = bbase + rg + i * 2;
        float m1 = 0.f, m2 = 0.f;
        #pragma unroll
        for (int k = 0; k < 8; ++k) {
            m1 += Mpart[((size_t)k << 20) + (size_t)b * 256 + h];
            m2 += Mpart[((size_t)k << 20) + (size_t)b * 256 + 128 + h];
        }
        float u = 1.0f / (1.0f + expf(-(m2 + bb2)));
        float t = tanhf(m1 + bb1);
        out[(size_t)b * 128 + h] = u * t + (1.0f - u) * accs[i];
    }
}

extern "C" void kernel_launch(void* const* d_in, const int* in_sizes, int n_in,
                              void* d_out, int out_size, void* d_ws, size_t ws_size,
                              hipStream_t stream) {
    const float* in0 = (const float*)d_in[0];
    const float* in1 = (const float*)d_in[1];
    const float* st0 = (const float*)d_in[2];
    const float* st1 = (const float*)d_in[3];
    const float* W1  = (const float*)d_in[4];
    const float* b1  = (const float*)d_in[5];
    const float* W2  = (const float*)d_in[6];
    const float* b2  = (const float*)d_in[7];
    const float* W3  = (const float*)d_in[8];
    float* out = (float*)d_out;
    char* ws = (char*)d_ws;

    unsigned char* Wt   = (unsigned char*)(ws + WT_OFF);
    unsigned*      x_bf = (unsigned*)(ws + XBF_OFF);
    float*         Mp   = (float*)(ws + MP_OFF);

    prep_wx<<<9216, 256, 0, stream>>>(W1, W2, in0, in1, (uint4*)Wt, x_bf);
    gemm_p<<<1024, 256, 0, stream>>>(Wt, st0, st1, (const __hip_bfloat16*)x_bf, Mp);
    epilogue<<<512, 256, 0, stream>>>(st0, st1, b1, b2, W3, Mp, out);
}

// Round 2
// 265.964 us; speedup vs baseline: 1.0453x; 1.0453x over previous
//
#include <hip/hip_runtime.h>
#include <hip/hip_bf16.h>
#include <stdint.h>

// ---------------------------------------------------------------------------
// TensorizedGRU: m[b,l] = sum_{j,k} s[b,j] x[b,k] W[l,j,k]  (l in [0,256): W1||W2)
// R11 = R9 structure (128-row tiles, grid 512, the 138.4us/44.6% config) with
// EXACTLY ONE change isolated: s-tile stored in LDS as f16.
//  - R10 post-mortem: 64-row tiles doubled VMEM B-frag instrs + L2 refetch
//    (FETCH 27.7->52MB) and that swamped the halved LDS return. Reverted.
//  - R9 round model: 695cyc/CU-round ~= 64x ds_read_b128 @ ~11cyc (LDS return
//    bound). f16 sv -> 64x ds_read_b64 @ ~6cyc = 384cyc < MFMA 310+eps.
//  - sv math: hv (f16x4) cvt to f32, pk_fma accumulate -> s applied at f32;
//    f16 rel err 2^-11 << bf16 noise (2^-8) already on x and W.
//  - Sl layout [32 j][132 r] f16: pad 132 -> fill writes 2-way/bank (free),
//    b64 reads 8B-aligned, 4-addr broadcast (16 lanes/addr).
// ws layout:
//   Wt   bf16 [256][65536]  @ 0          (33,554,432 B)  fragment-ordered
//   x_bf bf16 [4096][256]   @ 32MiB+2MiB ( 2,097,152 B)
//   Mpart f32 [8][4096][256]@ +2MiB      (33,554,432 B)
// ---------------------------------------------------------------------------

typedef short bf8 __attribute__((ext_vector_type(8)));   // 8 bf16 = 4 VGPRs
typedef float f32x4 __attribute__((ext_vector_type(4)));
typedef _Float16 h4 __attribute__((ext_vector_type(4))); // 4 f16 = 2 VGPRs

static constexpr size_t WT_OFF  = 0;
static constexpr size_t XBF_OFF = 33554432 + 2097152;
static constexpr size_t MP_OFF  = XBF_OFF + 2097152;

// round-to-nearest-even f32 -> bf16 (finite inputs only)
__device__ __forceinline__ unsigned f2bf(float f) {
    unsigned u = __builtin_bit_cast(unsigned, f);
    return (u + 0x7fffu + ((u >> 16) & 1u)) >> 16;
}
__device__ __forceinline__ unsigned pack2bf(float a, float b) {
    return f2bf(a) | (f2bf(b) << 16);
}

// ---------------- prep: fragment-ordered Wt (wave-per-frag) + x cast --------
// Fragment f = ((n16*1024 + kchunk)*2 + kst), f in [0, 32768).
// Blocks 0..8191: 4 waves/block, wave w makes frag f = bx*4 + w.
// Blocks 8192..9215: x = in0||in1 -> bf16.
__global__ void prep_wx(const float* __restrict__ W1, const float* __restrict__ W2,
                        const float* __restrict__ in0, const float* __restrict__ in1,
                        uint4* __restrict__ Wt, unsigned* __restrict__ x_bf) {
    int bx = blockIdx.x;
    if (bx < 8192) {
        const int tid  = threadIdx.x;
        const int lane = tid & 63, wave = tid >> 6;
        const unsigned f = bx * 4 + wave;
        const unsigned n16 = f >> 11;
        const unsigned kchunk = (f >> 1) & 1023u;
        const unsigned kst = f & 1u;
        const unsigned n = n16 * 16 + (lane & 15);
        const unsigned K = kchunk * 64 + kst * 32 + (lane >> 4) * 8;
        const float* src = (n < 128 ? W1 + ((size_t)n << 16)
                                    : W2 + ((size_t)(n - 128) << 16)) + K;
        float4 a = ((const float4*)src)[0];
        float4 b = ((const float4*)src)[1];
        uint4 o;
        o.x = pack2bf(a.x, a.y); o.y = pack2bf(a.z, a.w);
        o.z = pack2bf(b.x, b.y); o.w = pack2bf(b.z, b.w);
        Wt[(size_t)f * 64 + lane] = o;        // contiguous 1KB per wave
    } else {
        unsigned v = (bx - 8192) * 256 + threadIdx.x; // 262,144 units of 4 elems
        unsigned b = v >> 6;
        unsigned j4 = (v & 63u) * 4u;
        const float* src = (j4 < 128) ? (in0 + (size_t)b * 128 + j4)
                                      : (in1 + (size_t)b * 128 + (j4 - 128));
        float4 a = *(const float4*)src;
        uint2 o;
        o.x = pack2bf(a.x, a.y);
        o.y = pack2bf(a.z, a.w);
        ((uint2*)x_bf)[v] = o;
    }
}

// ---------------- main GEMM: 128x128 tile, split-K=8, barrier-free ----------
// grid 512: ks = bx&7 (XCD-pinned), nt = (bx>>3)&1, mt = bx>>4 (0..31).
// block 256 = 4 waves; wave w owns n-cols [w*32, w*32+32), all 128 m-rows.
__launch_bounds__(256, 2)
__global__ void gemm_p(const unsigned char* __restrict__ Wt,
                       const float* __restrict__ st0, const float* __restrict__ st1,
                       const __hip_bfloat16* __restrict__ x_bf,
                       float* __restrict__ Mpart) {
    const int bx = blockIdx.x;
    const int ks = bx & 7;                  // split-K slice, pinned per XCD
    const int nt = (bx >> 3) & 1;
    const int mt = bx >> 4;
    const int b0 = mt << 7, n0 = nt << 7;
    const int tid  = threadIdx.x;
    const int lane = tid & 63, wave = tid >> 6;
    const int l15 = lane & 15, l4 = lane >> 4;

    // s tile as f16: [32 j][132 r]  (8448 B; half the LDS return bytes of R9)
    __shared__ __align__(16) _Float16 SlH[32 * 132];
    for (int idx = tid; idx < 4096; idx += 256) {
        int r = idx >> 5, j = idx & 31;     // j-fast: coalesced st reads
        int jg = ks * 32 + j;
        float v = (jg < 128) ? st0[(size_t)(b0 + r) * 128 + jg]
                             : st1[(size_t)(b0 + r) * 128 + (jg - 128)];
        SlH[j * 132 + r] = (_Float16)v;
    }
    __syncthreads();                        // the ONLY barrier

    // B-frag bases, fragment-ordered Wt:
    // n16(nf) = nt*8 + wave*2 + nf; frag addr = ((n16*1024+kchunk)*2+kst)*1024 + lane*16
    const unsigned char* rbn[2];
    #pragma unroll
    for (int nf = 0; nf < 2; ++nf)
        rbn[nf] = Wt + ((size_t)(nt * 8 + wave * 2 + nf) << 21) + lane * 16;
    const _Float16* sB = SlH + l4 * 4;

    f32x4 racc[8][2];
    #pragma unroll
    for (int mf = 0; mf < 8; ++mf)
        #pragma unroll
        for (int nf = 0; nf < 2; ++nf)
            racc[mf][nf] = (f32x4){0.f, 0.f, 0.f, 0.f};
    const f32x4 zacc = (f32x4){0.f, 0.f, 0.f, 0.f};

    // chunk c in [0,128): q = c>>5 (x-quadrant), j = c&31 (local j)
    // kchunk(c) = ((ks*32 + j)*4 + q); byte offset = kchunk*2048 (+ kst*1024)
    auto kof = [&](int c) { return (size_t)(((ks * 32 + (c & 31)) * 4 + (c >> 5)) * 2048); };

    bf8 buf[2][2][2];                       // [ping][nf][kst]
    #pragma unroll
    for (int nf = 0; nf < 2; ++nf)
        #pragma unroll
        for (int kst = 0; kst < 2; ++kst)
            buf[0][nf][kst] = *(const bf8*)(rbn[nf] + kof(0) + kst * 1024);

    bf8 a[8][2];                            // x A-frags, reloaded at q boundary

    #pragma unroll 2
    for (int c = 0; c < 128; ++c) {
        const int pp = c & 1;
        const int q = c >> 5, j = c & 31;
        if (j == 0) {                       // new x-quadrant: reload A-frags
            const __hip_bfloat16* xb = x_bf + q * 64 + l4 * 8;
            #pragma unroll
            for (int mf = 0; mf < 8; ++mf)
                #pragma unroll
                for (int kst = 0; kst < 2; ++kst)
                    a[mf][kst] = *(const bf8*)(xb + (size_t)(b0 + mf * 16 + l15) * 256 + kst * 32);
        }
        // prefetch next chunk's B-frags (wraps to 0 on last iter: harmless)
        {
            const size_t k1 = kof((c + 1) & 127);
            #pragma unroll
            for (int nf = 0; nf < 2; ++nf)
                #pragma unroll
                for (int kst = 0; kst < 2; ++kst)
                    buf[pp ^ 1][nf][kst] = *(const bf8*)(rbn[nf] + k1 + kst * 1024);
        }
        // s broadcast values for this j (f16 -> f32), then 32 MFMA + scale-acc
        #pragma unroll
        for (int mf = 0; mf < 8; ++mf) {
            h4 hv = *(const h4*)(sB + j * 132 + mf * 16);   // ds_read_b64 broadcast
            f32x4 sf;
            #pragma unroll
            for (int r = 0; r < 4; ++r) sf[r] = (float)hv[r];
            #pragma unroll
            for (int nf = 0; nf < 2; ++nf) {
                f32x4 m0 = __builtin_amdgcn_mfma_f32_16x16x32_bf16(a[mf][0], buf[pp][nf][0], zacc, 0, 0, 0);
                m0 = __builtin_amdgcn_mfma_f32_16x16x32_bf16(a[mf][1], buf[pp][nf][1], m0, 0, 0, 0);
                racc[mf][nf] += sf * m0;
            }
        }
    }

    // split-K partial stores (regular stores: producer->consumer coherence)
    float* mp = Mpart + ((size_t)ks << 20);
    #pragma unroll
    for (int mf = 0; mf < 8; ++mf)
        #pragma unroll
        for (int nf = 0; nf < 2; ++nf) {
            int b = b0 + mf * 16 + l4 * 4;
            int n = n0 + wave * 32 + nf * 16 + l15;
            #pragma unroll
            for (int r = 0; r < 4; ++r)
                mp[(size_t)(b + r) * 256 + n] = racc[mf][nf][r];
        }
}

// ---------------- epilogue: reduce split-K, s@W3, activations, blend --------
__global__ void epilogue(const float* __restrict__ st0, const float* __restrict__ st1,
                         const float* __restrict__ b1, const float* __restrict__ b2,
                         const float* __restrict__ W3, const float* __restrict__ Mpart,
                         float* __restrict__ out) {
    const int tid = threadIdx.x;
    const int h = tid & 127, rg = tid >> 7;          // rg in {0,1}
    const int bbase = blockIdx.x * 8;                // 8 rows per block
    __shared__ float srow[8][256];
    #pragma unroll
    for (int i = 0; i < 8; ++i) {
        int idx = i * 256 + tid;
        int r = idx >> 8, j = idx & 255;
        float v = (j < 128) ? st0[(size_t)(bbase + r) * 128 + j]
                            : st1[(size_t)(bbase + r) * 128 + (j - 128)];
        srow[r][j] = v;
    }
    __syncthreads();
    float acc0 = 0.f, acc1 = 0.f, acc2 = 0.f, acc3 = 0.f;
    for (int j = 0; j < 256; ++j) {
        float w = W3[j * 128 + h];
        acc0 += srow[rg][j] * w;
        acc1 += srow[rg + 2][j] * w;
        acc2 += srow[rg + 4][j] * w;
        acc3 += srow[rg + 6][j] * w;
    }
    float accs[4] = {acc0, acc1, acc2, acc3};
    float bb1 = b1[h], bb2 = b2[h];
    #pragma unroll
    for (int i = 0; i < 4; ++i) {
        int b = bbase + rg + i * 2;
        float m1 = 0.f, m2 = 0.f;
        #pragma unroll
        for (int k = 0; k < 8; ++k) {
            m1 += Mpart[((size_t)k << 20) + (size_t)b * 256 + h];
            m2 += Mpart[((size_t)k << 20) + (size_t)b * 256 + 128 + h];
        }
        float u = 1.0f / (1.0f + expf(-(m2 + bb2)));
        float t = tanhf(m1 + bb1);
        out[(size_t)b * 128 + h] = u * t + (1.0f - u) * accs[i];
    }
}

extern "C" void kernel_launch(void* const* d_in, const int* in_sizes, int n_in,
                              void* d_out, int out_size, void* d_ws, size_t ws_size,
                              hipStream_t stream) {
    const float* in0 = (const float*)d_in[0];
    const float* in1 = (const float*)d_in[1];
    const float* st0 = (const float*)d_in[2];
    const float* st1 = (const float*)d_in[3];
    const float* W1  = (const float*)d_in[4];
    const float* b1  = (const float*)d_in[5];
    const float* W2  = (const float*)d_in[6];
    const float* b2  = (const float*)d_in[7];
    const float* W3  = (const float*)d_in[8];
    float* out = (float*)d_out;
    char* ws = (char*)d_ws;

    unsigned char* Wt   = (unsigned char*)(ws + WT_OFF);
    unsigned*      x_bf = (unsigned*)(ws + XBF_OFF);
    float*         Mp   = (float*)(ws + MP_OFF);

    prep_wx<<<9216, 256, 0, stream>>>(W1, W2, in0, in1, (uint4*)Wt, x_bf);
    gemm_p<<<512, 256, 0, stream>>>(Wt, st0, st1, (const __hip_bfloat16*)x_bf, Mp);
    epilogue<<<512, 256, 0, stream>>>(st0, st1, b1, b2, W3, Mp, out);
}

// Round 3
// 251.819 us; speedup vs baseline: 1.1040x; 1.0562x over previous
//
#include <hip/hip_runtime.h>
#include <hip/hip_bf16.h>
#include <stdint.h>

// ---------------------------------------------------------------------------
// TensorizedGRU: m[b,l] = sum_{j,k} s[b,j] x[b,k] W[l,j,k]  (l in [0,256): W1||W2)
// R12 = R9 math/tiles/occupancy (128x128, grid 512, f32 s, the 138.4us config)
// with the per-wave ADDRESSING path minimized:
//  - R10/R11 post-mortem: round time tracks per-wave instruction path ~1:1
//    (R11: +64cyc cvt/wave -> +129cyc/round); no shared pipe >50%. The kernel
//    is issue/dependency serialized, and ~100 VALU instr/chunk was addressing
//    (kof() 64-bit math x4 loads, j*132 LDS addrs, j==0 branch).
//  - Fix: q(4) x jb(4) x jj(unroll 8) loops; SGPR Wt base (readfirstlane) +
//    ONE running 32-bit voffset (vo += 8192/chunk), kst*1024 in load imm;
//    s-ptr += 132/chunk with mf*64B in ds_read imm; A reloaded per q;
//    (q,0) B direct-loaded per q (kills wrap logic; ~10cyc/chunk amortized).
//  - Per-chunk VALU ~165 -> ~35-70 instr. MFMA/LDS/FETCH volumes unchanged.
// ws layout:
//   Wt   bf16 [256][65536]  @ 0          (33,554,432 B)  fragment-ordered
//   x_bf bf16 [4096][256]   @ 32MiB+2MiB ( 2,097,152 B)
//   Mpart f32 [8][4096][256]@ +2MiB      (33,554,432 B)
// ---------------------------------------------------------------------------

typedef short bf8 __attribute__((ext_vector_type(8)));   // 8 bf16 = 4 VGPRs
typedef float f32x4 __attribute__((ext_vector_type(4)));

static constexpr size_t WT_OFF  = 0;
static constexpr size_t XBF_OFF = 33554432 + 2097152;
static constexpr size_t MP_OFF  = XBF_OFF + 2097152;

// round-to-nearest-even f32 -> bf16 (finite inputs only)
__device__ __forceinline__ unsigned f2bf(float f) {
    unsigned u = __builtin_bit_cast(unsigned, f);
    return (u + 0x7fffu + ((u >> 16) & 1u)) >> 16;
}
__device__ __forceinline__ unsigned pack2bf(float a, float b) {
    return f2bf(a) | (f2bf(b) << 16);
}

// ---------------- prep: fragment-ordered Wt (wave-per-frag) + x cast --------
// Fragment f = ((n16*1024 + kchunk)*2 + kst), f in [0, 32768).
// Blocks 0..8191: 4 waves/block, wave w makes frag f = bx*4 + w.
// Blocks 8192..9215: x = in0||in1 -> bf16.
__global__ void prep_wx(const float* __restrict__ W1, const float* __restrict__ W2,
                        const float* __restrict__ in0, const float* __restrict__ in1,
                        uint4* __restrict__ Wt, unsigned* __restrict__ x_bf) {
    int bx = blockIdx.x;
    if (bx < 8192) {
        const int tid  = threadIdx.x;
        const int lane = tid & 63, wave = tid >> 6;
        const unsigned f = bx * 4 + wave;
        const unsigned n16 = f >> 11;
        const unsigned kchunk = (f >> 1) & 1023u;
        const unsigned kst = f & 1u;
        const unsigned n = n16 * 16 + (lane & 15);
        const unsigned K = kchunk * 64 + kst * 32 + (lane >> 4) * 8;
        const float* src = (n < 128 ? W1 + ((size_t)n << 16)
                                    : W2 + ((size_t)(n - 128) << 16)) + K;
        float4 a = ((const float4*)src)[0];
        float4 b = ((const float4*)src)[1];
        uint4 o;
        o.x = pack2bf(a.x, a.y); o.y = pack2bf(a.z, a.w);
        o.z = pack2bf(b.x, b.y); o.w = pack2bf(b.z, b.w);
        Wt[(size_t)f * 64 + lane] = o;        // contiguous 1KB per wave
    } else {
        unsigned v = (bx - 8192) * 256 + threadIdx.x; // 262,144 units of 4 elems
        unsigned b = v >> 6;
        unsigned j4 = (v & 63u) * 4u;
        const float* src = (j4 < 128) ? (in0 + (size_t)b * 128 + j4)
                                      : (in1 + (size_t)b * 128 + (j4 - 128));
        float4 a = *(const float4*)src;
        uint2 o;
        o.x = pack2bf(a.x, a.y);
        o.y = pack2bf(a.z, a.w);
        ((uint2*)x_bf)[v] = o;
    }
}

// ---------------- main GEMM: 128x128 tile, split-K=8, barrier-free ----------
// grid 512: ks = bx&7 (XCD-pinned), nt = (bx>>3)&1, mt = bx>>4 (0..31).
// block 256 = 4 waves; wave w owns n-cols [w*32, w*32+32), all 128 m-rows.
__launch_bounds__(256, 2)
__global__ void gemm_p(const unsigned char* __restrict__ Wt,
                       const float* __restrict__ st0, const float* __restrict__ st1,
                       const __hip_bfloat16* __restrict__ x_bf,
                       float* __restrict__ Mpart) {
    const int bx = blockIdx.x;
    const int ks = bx & 7;                  // split-K slice, pinned per XCD
    const int nt = (bx >> 3) & 1;
    const int mt = bx >> 4;
    const int b0 = mt << 7, n0 = nt << 7;
    const int tid  = threadIdx.x;
    const int lane = tid & 63, wave = tid >> 6;
    const int l15 = lane & 15, l4 = lane >> 4;

    // s tile: [32 j][132 r] f32 (pad to 132 -> broadcast-clean)
    __shared__ __align__(16) float Sl[32 * 132];
    for (int idx = tid; idx < 4096; idx += 256) {
        int r = idx >> 5, j = idx & 31;
        int jg = ks * 32 + j;
        float v = (jg < 128) ? st0[(size_t)(b0 + r) * 128 + jg]
                             : st1[(size_t)(b0 + r) * 128 + (jg - 128)];
        Sl[j * 132 + r] = v;
    }
    __syncthreads();                        // the ONLY barrier

    // Wave-uniform Wt slice bases in SGPRs: n16(nf) = nt*8 + wave*2 + nf.
    const int n16_0 = __builtin_amdgcn_readfirstlane(nt * 8 + wave * 2 + 0);
    const int n16_1 = __builtin_amdgcn_readfirstlane(nt * 8 + wave * 2 + 1);
    const unsigned char* wb0 = Wt + ((size_t)n16_0 << 21);
    const unsigned char* wb1 = Wt + ((size_t)n16_1 << 21);

    f32x4 racc[8][2];
    #pragma unroll
    for (int mf = 0; mf < 8; ++mf)
        #pragma unroll
        for (int nf = 0; nf < 2; ++nf)
            racc[mf][nf] = (f32x4){0.f, 0.f, 0.f, 0.f};
    const f32x4 zacc = (f32x4){0.f, 0.f, 0.f, 0.f};

    bf8 a[8][2];                            // x A-frags, reloaded per quadrant
    bf8 buf[2][2][2];                       // [ping][nf][kst] B-frags

    // Running within-slice byte offset: vo(q,j) = lane*16 + ks*262144 + q*2048
    //                                           + j*8192   (kst*1024 in imm)
    unsigned vo = (unsigned)lane * 16u + (unsigned)ks * 262144u;

    for (int q = 0; q < 4; ++q) {
        // A-frags for this x-quadrant (x_bf is L2-resident, 2MB)
        #pragma unroll
        for (int mf = 0; mf < 8; ++mf) {
            const __hip_bfloat16* xp =
                x_bf + (size_t)((b0 + mf * 16 + l15) * 256 + q * 64 + l4 * 8);
            a[mf][0] = *(const bf8*)(xp);
            a[mf][1] = *(const bf8*)(xp + 32);
        }
        // direct-load j=0 B-frags (one exposed latency per 32 chunks)
        buf[0][0][0] = *(const bf8*)(wb0 + vo);
        buf[0][0][1] = *(const bf8*)(wb0 + vo + 1024);
        buf[0][1][0] = *(const bf8*)(wb1 + vo);
        buf[0][1][1] = *(const bf8*)(wb1 + vo + 1024);
        vo += 8192;                          // -> prefetch target j=1

        const float* svp = Sl + l4 * 4;      // s row-broadcast ptr, +132/chunk

        for (int jb = 0; jb < 4; ++jb) {
            #pragma unroll
            for (int jj = 0; jj < 8; ++jj) {
                const int pp = jj & 1;       // compile-time ping-pong
                // prefetch next chunk's B-frags (last chunk of q prefetches
                // 2KB past the j-range: lands in valid ws, overwritten unused)
                buf[pp ^ 1][0][0] = *(const bf8*)(wb0 + vo);
                buf[pp ^ 1][0][1] = *(const bf8*)(wb0 + vo + 1024);
                buf[pp ^ 1][1][0] = *(const bf8*)(wb1 + vo);
                buf[pp ^ 1][1][1] = *(const bf8*)(wb1 + vo + 1024);
                vo += 8192;
                // s broadcast values for this j (imm-folded mf*64B)
                f32x4 sv[8];
                #pragma unroll
                for (int mf = 0; mf < 8; ++mf)
                    sv[mf] = *(const f32x4*)(svp + mf * 16);
                svp += 132;
                // 32 MFMA + f32 scale-accumulate
                #pragma unroll
                for (int nf = 0; nf < 2; ++nf) {
                    bf8 bf0 = buf[pp][nf][0];
                    bf8 bf1 = buf[pp][nf][1];
                    #pragma unroll
                    for (int mf = 0; mf < 8; ++mf) {
                        f32x4 m0 = __builtin_amdgcn_mfma_f32_16x16x32_bf16(a[mf][0], bf0, zacc, 0, 0, 0);
                        m0 = __builtin_amdgcn_mfma_f32_16x16x32_bf16(a[mf][1], bf1, m0, 0, 0, 0);
                        racc[mf][nf] += sv[mf] * m0;
                    }
                }
            }
        }
        vo += 2048 - 33 * 8192;              // rewind to (q+1, j=0)
    }

    // split-K partial stores (regular stores: producer->consumer coherence)
    float* mp = Mpart + ((size_t)ks << 20);
    #pragma unroll
    for (int mf = 0; mf < 8; ++mf)
        #pragma unroll
        for (int nf = 0; nf < 2; ++nf) {
            int b = b0 + mf * 16 + l4 * 4;
            int n = n0 + wave * 32 + nf * 16 + l15;
            #pragma unroll
            for (int r = 0; r < 4; ++r)
                mp[(size_t)(b + r) * 256 + n] = racc[mf][nf][r];
        }
}

// ---------------- epilogue: reduce split-K, s@W3, activations, blend --------
__global__ void epilogue(const float* __restrict__ st0, const float* __restrict__ st1,
                         const float* __restrict__ b1, const float* __restrict__ b2,
                         const float* __restrict__ W3, const float* __restrict__ Mpart,
                         float* __restrict__ out) {
    const int tid = threadIdx.x;
    const int h = tid & 127, rg = tid >> 7;          // rg in {0,1}
    const int bbase = blockIdx.x * 8;                // 8 rows per block
    __shared__ float srow[8][256];
    #pragma unroll
    for (int i = 0; i < 8; ++i) {
        int idx = i * 256 + tid;
        int r = idx >> 8, j = idx & 255;
        float v = (j < 128) ? st0[(size_t)(bbase + r) * 128 + j]
                            : st1[(size_t)(bbase + r) * 128 + (j - 128)];
        srow[r][j] = v;
    }
    __syncthreads();
    float acc0 = 0.f, acc1 = 0.f, acc2 = 0.f, acc3 = 0.f;
    for (int j = 0; j < 256; ++j) {
        float w = W3[j * 128 + h];
        acc0 += srow[rg][j] * w;
        acc1 += srow[rg + 2][j] * w;
        acc2 += srow[rg + 4][j] * w;
        acc3 += srow[rg + 6][j] * w;
    }
    float accs[4] = {acc0, acc1, acc2, acc3};
    float bb1 = b1[h], bb2 = b2[h];
    #pragma unroll
    for (int i = 0; i < 4; ++i) {
        int b = bbase + rg + i * 2;
        float m1 = 0.f, m2 = 0.f;
        #pragma unroll
        for (int k = 0; k < 8; ++k) {
            m1 += Mpart[((size_t)k << 20) + (size_t)b * 256 + h];
            m2 += Mpart[((size_t)k << 20) + (size_t)b * 256 + 128 + h];
        }
        float u = 1.0f / (1.0f + expf(-(m2 + bb2)));
        float t = tanhf(m1 + bb1);
        out[(size_t)b * 128 + h] = u * t + (1.0f - u) * accs[i];
    }
}

extern "C" void kernel_launch(void* const* d_in, const int* in_sizes, int n_in,
                              void* d_out, int out_size, void* d_ws, size_t ws_size,
                              hipStream_t stream) {
    const float* in0 = (const float*)d_in[0];
    const float* in1 = (const float*)d_in[1];
    const float* st0 = (const float*)d_in[2];
    const float* st1 = (const float*)d_in[3];
    const float* W1  = (const float*)d_in[4];
    const float* b1  = (const float*)d_in[5];
    const float* W2  = (const float*)d_in[6];
    const float* b2  = (const float*)d_in[7];
    const float* W3  = (const float*)d_in[8];
    float* out = (float*)d_out;
    char* ws = (char*)d_ws;

    unsigned char* Wt   = (unsigned char*)(ws + WT_OFF);
    unsigned*      x_bf = (unsigned*)(ws + XBF_OFF);
    float*         Mp   = (float*)(ws + MP_OFF);

    prep_wx<<<9216, 256, 0, stream>>>(W1, W2, in0, in1, (uint4*)Wt, x_bf);
    gemm_p<<<512, 256, 0, stream>>>(Wt, st0, st1, (const __hip_bfloat16*)x_bf, Mp);
    epilogue<<<512, 256, 0, stream>>>(st0, st1, b1, b2, W3, Mp, out);
}